// Round 11
// baseline (1098.648 us; speedup 1.0000x reference)
//
#include <hip/hip_runtime.h>
#include <hip/hip_bf16.h>
#include <cstdio>

typedef unsigned short u16;
typedef __bf16 bf16x8 __attribute__((ext_vector_type(8)));
typedef float  floatx4 __attribute__((ext_vector_type(4)));

// ---------- scalar helpers ----------
__device__ __forceinline__ float bf2f(u16 u) {
  union { unsigned int i; float f; } v; v.i = ((unsigned int)u) << 16; return v.f;
}
__device__ __forceinline__ u16 f2bf(float f) {
  union { float f; unsigned int i; } v; v.f = f;
  unsigned int x = v.i;
  return (u16)((x + 0x7fffu + ((x >> 16) & 1u)) >> 16);   // RNE
}
__device__ __forceinline__ unsigned int f2bf_pk(float a, float b) {   // [lo=a, hi=b]
  __hip_bfloat162 h = __float22bfloat162_rn(make_float2(a, b));
  union { __hip_bfloat162 h; unsigned int u; } v; v.h = h; return v.u;
}
// fast gates: v_rcp (~1 ulp) + native exp — no IEEE div
__device__ __forceinline__ float sigmoidf_(float x) {
  return __builtin_amdgcn_rcpf(1.f + __expf(-x));
}
__device__ __forceinline__ float tanhf_(float x) {
  return fmaf(-2.f, __builtin_amdgcn_rcpf(1.f + __expf(2.f * x)), 1.f);
}

// LDS swizzle, 128-elem rows, 16B chunks: chunk' = chunk ^ (row&15)
__device__ __forceinline__ int swz128(int row, int c16) {
  return row * 128 + ((c16 ^ (row & 15)) << 3);
}
// element-level access into swizzled rows (consistent with swz128 chunks)
__device__ __forceinline__ int swze(int row, int col) {
  return row * 128 + (((((col >> 3)) ^ (row & 15)) << 3) | (col & 7));
}

// one gate GEMM pass: A = CM child rows from LDS, 16 cols (this lane's col), K=128
template<int NCI>
__device__ __forceinline__ void gate_pass(const u16* ldsA, const u16* __restrict__ BT,
                                          int col, int l16, int quad, floatx4 (&acc)[NCI])
{
  bf16x8 b[4];
#pragma unroll
  for (int ks = 0; ks < 4; ks++)
    b[ks] = *reinterpret_cast<const bf16x8*>(BT + (size_t)col * 128 + ks * 32 + quad * 8);
#pragma unroll
  for (int i = 0; i < NCI; i++) acc[i] = (floatx4){0.f, 0.f, 0.f, 0.f};
#pragma unroll
  for (int ks = 0; ks < 4; ks++)
#pragma unroll
    for (int i = 0; i < NCI; i++) {
      bf16x8 a = *reinterpret_cast<const bf16x8*>(&ldsA[swz128(i * 16 + l16, ks * 4 + quad)]);
      acc[i] = __builtin_amdgcn_mfma_f32_16x16x32_bf16(a, b[ks], acc[i], 0, 0, 0);
    }
}

// ============ proj_e: E'[v][512] = emb[v] @ [Wix|Wux|Wox|Wfx] + bias (bf16) ============
__global__ __launch_bounds__(256) void proj_e(
    const float* __restrict__ emb, const u16* __restrict__ WT,
    const float* __restrict__ bsum, u16* __restrict__ Ep)
{
  __shared__ __align__(16) u16 ldsA[128 * 128];
  const int tid = threadIdx.x;
  const long m0 = (long)blockIdx.x * 128;
  const int n0 = blockIdx.y * 128;
  {
    const int r = tid >> 1, half = tid & 1;
    long row = m0 + r; if (row > 49999) row = 49999;
    const float* src = emb + row * 128 + half * 64;
#pragma unroll
    for (int i = 0; i < 8; i++) {
      float4 v0 = *reinterpret_cast<const float4*>(src + i * 8);
      float4 v1 = *reinterpret_cast<const float4*>(src + i * 8 + 4);
      unsigned int ov[4] = { f2bf_pk(v0.x, v0.y), f2bf_pk(v0.z, v0.w),
                             f2bf_pk(v1.x, v1.y), f2bf_pk(v1.z, v1.w) };
      *reinterpret_cast<uint4*>(&ldsA[swz128(r, half * 8 + i)]) =
          *reinterpret_cast<const uint4*>(ov);
    }
  }
  __syncthreads();
  const int lane = tid & 63, w = tid >> 6, l16 = lane & 15, quad = lane >> 4;
#pragma unroll
  for (int gl = 0; gl < 2; gl++) {
    const int col = n0 + w * 32 + gl * 16 + l16;
    floatx4 acc[8];
    gate_pass<8>(ldsA, WT, col, l16, quad, acc);
    const float bb = bsum[col];
#pragma unroll
    for (int i = 0; i < 8; i++)
#pragma unroll
      for (int r2 = 0; r2 < 4; r2++) {
        const long row = m0 + i * 16 + quad * 4 + r2;
        if (row < 50000) Ep[row * 512 + col] = f2bf(acc[i][r2] + bb);
      }
  }
}

// ============ k_level: fused f+i+u+o over CHILD rows, group-sum epilogues ============
// Register-lean pipeline (round 10 spilled ~300 MB at 128 arch-VGPRs):
//   per gl: f-pass -> fs regs; i-pass -> ip regs; u-pass -> c written to ldsC
//   (fs, ip die); o-pass -> oPre regs (only cross-pass state).
// After barrier: h = sig(oPre+Ep_o) * tanh(ldsC) staged into ldsA; dense stores.
template<int LR, bool LEAF>
__global__ __launch_bounds__(256, 2) void k_level(
    const int* __restrict__ sen, const u16* __restrict__ Ep,
    const u16* __restrict__ h_prev, const u16* __restrict__ c_prev,
    const u16* __restrict__ BfT, const u16* __restrict__ BihT,
    const u16* __restrict__ BuhT, const u16* __restrict__ BohT,
    u16* __restrict__ c_out, u16* __restrict__ h_out,
    long o0, long co0)
{
  constexpr int PM  = (LR == 2) ? 32 : 64;
  constexpr int CM  = PM << LR;
  constexpr int NCI = CM / 16;
  constexpr int RT  = 1 << LR;
  constexpr int RTI = 4 >> LR;         // parents per quad-block of 4 child rows
  constexpr int TPR = 256 / CM;        // staging threads per child row
  __shared__ __align__(16) u16 ldsA[CM * 128];   // child h (swz); h store stage later
  __shared__ __align__(16) u16 ldsC[PM * 128];   // LEAF: child c -> parent c; else parent c
  __shared__ int sidP[PM];

  const int tid = threadIdx.x;
  const long p0 = (long)blockIdx.x * PM;
  const long cb = (long)blockIdx.x * CM;

  // ---- stage children ----
  {
    const int r = tid / TPR, q = tid % TPR;
    constexpr int CH = 16 / TPR;
    if (LEAF) {
      const u16* e = Ep + (size_t)sen[co0 + cb + r] * 512;
#pragma unroll
      for (int ii = 0; ii < CH; ii++) {
        const int c16 = q * CH + ii;
        uint4 vi = *reinterpret_cast<const uint4*>(e + c16 * 8);
        uint4 vu = *reinterpret_cast<const uint4*>(e + 128 + c16 * 8);
        uint4 vo = *reinterpret_cast<const uint4*>(e + 256 + c16 * 8);
        const u16* pi = reinterpret_cast<const u16*>(&vi);
        const u16* pu = reinterpret_cast<const u16*>(&vu);
        const u16* po = reinterpret_cast<const u16*>(&vo);
        unsigned int hc[4], cc[4];
#pragma unroll
        for (int k = 0; k < 4; k++) {
          float cv0 = sigmoidf_(bf2f(pi[2*k]))   * tanhf_(bf2f(pu[2*k]));
          float cv1 = sigmoidf_(bf2f(pi[2*k+1])) * tanhf_(bf2f(pu[2*k+1]));
          float h0 = sigmoidf_(bf2f(po[2*k]))   * tanhf_(cv0);
          float h1 = sigmoidf_(bf2f(po[2*k+1])) * tanhf_(cv1);
          cc[k] = f2bf_pk(cv0, cv1);
          hc[k] = f2bf_pk(h0, h1);
        }
        *reinterpret_cast<uint4*>(&ldsA[swz128(r, c16)]) = *reinterpret_cast<const uint4*>(hc);
        *reinterpret_cast<uint4*>(&ldsC[swz128(r, c16)]) = *reinterpret_cast<const uint4*>(cc);
      }
    } else {
      const u16* src = h_prev + (cb + r) * 128;
#pragma unroll
      for (int ii = 0; ii < CH; ii++) {
        const int c16 = q * CH + ii;
        *reinterpret_cast<uint4*>(&ldsA[swz128(r, c16)]) =
            *reinterpret_cast<const uint4*>(src + c16 * 8);
      }
    }
    if (tid < PM) sidP[tid] = sen[o0 + p0 + tid];
  }
  __syncthreads();

  const int lane = tid & 63, w = tid >> 6, l16 = lane & 15, quad = lane >> 4;

  float oPre[2][NCI][RTI];   // only state surviving all passes

#pragma unroll
  for (int gl = 0; gl < 2; gl++) {
    const int col = w * 32 + gl * 16 + l16;
    floatx4 acc[NCI];

    // ---- f pass -> fs (LEAF reads child c from ldsC BEFORE u overwrites it) ----
    float fs[NCI][RTI];
    gate_pass<NCI>(ldsA, BfT, col, l16, quad, acc);
#pragma unroll
    for (int i = 0; i < NCI; i++) {
      const int rbase = i * 16 + quad * 4;
#pragma unroll
      for (int t = 0; t < RTI; t++) {
        const int p = (rbase >> LR) + t;
        const float epf = bf2f(Ep[(size_t)sidP[p] * 512 + 384 + col]);
        float s = 0.f;
#pragma unroll
        for (int r2 = t * RT; r2 < t * RT + RT; r2++) {
          const int row = rbase + r2;
          const float cch = LEAF ? bf2f(ldsC[swze(row, col)])
                                 : bf2f(c_prev[(cb + row) * 128 + col]);
          s += sigmoidf_(acc[i][r2] + epf) * cch;
        }
        fs[i][t] = s;
      }
    }

    // ---- i pass -> ip ----
    float ip[NCI][RTI];
    gate_pass<NCI>(ldsA, BihT, col, l16, quad, acc);
#pragma unroll
    for (int i = 0; i < NCI; i++)
#pragma unroll
      for (int t = 0; t < RTI; t++) {
        float s = 0.f;
#pragma unroll
        for (int r2 = t * RT; r2 < t * RT + RT; r2++) s += acc[i][r2];
        ip[i][t] = s;
      }

    // ---- u pass + combine -> c into ldsC (fs, ip die here) ----
    gate_pass<NCI>(ldsA, BuhT, col, l16, quad, acc);
#pragma unroll
    for (int i = 0; i < NCI; i++) {
      const int pb = (i * 16 + quad * 4) >> LR;
#pragma unroll
      for (int t = 0; t < RTI; t++) {
        float us = 0.f;
#pragma unroll
        for (int r2 = t * RT; r2 < t * RT + RT; r2++) us += acc[i][r2];
        const int p = pb + t;
        const size_t eb = (size_t)sidP[p] * 512;
        const float preI = ip[i][t] + bf2f(Ep[eb + col]);
        const float preU = us + bf2f(Ep[eb + 128 + col]);
        const float c = sigmoidf_(preI) * tanhf_(preU) + fs[i][t];
        ldsC[swze(p, col)] = f2bf(c);   // same-lane ownership
      }
    }

    // ---- o pass -> oPre ----
    gate_pass<NCI>(ldsA, BohT, col, l16, quad, acc);
#pragma unroll
    for (int i = 0; i < NCI; i++)
#pragma unroll
      for (int t = 0; t < RTI; t++) {
        float s = 0.f;
#pragma unroll
        for (int r2 = t * RT; r2 < t * RT + RT; r2++) s += acc[i][r2];
        oPre[gl][i][t] = s;
      }
  }
  __syncthreads();   // all MFMA reads of ldsA done — reuse rows 0..PM-1 for h staging

  // ---- h epilogue: h = sig(oPre + Ep_o) * tanh(c from ldsC) ----
#pragma unroll
  for (int gl = 0; gl < 2; gl++) {
    const int col = w * 32 + gl * 16 + l16;
#pragma unroll
    for (int i = 0; i < NCI; i++) {
      const int pb = (i * 16 + quad * 4) >> LR;
#pragma unroll
      for (int t = 0; t < RTI; t++) {
        const int p = pb + t;
        const float cc = bf2f(ldsC[swze(p, col)]);
        const float h = sigmoidf_(oPre[gl][i][t] + bf2f(Ep[(size_t)sidP[p] * 512 + 256 + col]))
                      * tanhf_(cc);
        ldsA[swze(p, col)] = f2bf(h);
      }
    }
  }
  __syncthreads();

  // ---- dense stores: c from ldsC, h from ldsA ----
  u16* cdst = c_out + p0 * 128;
  u16* hdst = h_out + p0 * 128;
  for (int t = tid; t < PM * 16; t += 256) {
    const int r = t >> 4, c16 = t & 15;
    *reinterpret_cast<uint4*>(cdst + t * 8) = *reinterpret_cast<const uint4*>(&ldsC[swz128(r, c16)]);
    *reinterpret_cast<uint4*>(hdst + t * 8) = *reinterpret_cast<const uint4*>(&ldsA[swz128(r, c16)]);
  }
}

// ---------- weight/bias prep ----------
__global__ void build_wallT(const float* __restrict__ Wix, const float* __restrict__ Wux,
                            const float* __restrict__ Wox, const float* __restrict__ Wfx,
                            u16* __restrict__ WT)
{
  int idx = blockIdx.x * 256 + threadIdx.x;   // 512*128
  int n = idx >> 7, k = idx & 127;
  int g = n >> 7, j = n & 127;
  const float* W = (g == 0) ? Wix : (g == 1) ? Wux : (g == 2) ? Wox : Wfx;
  WT[idx] = f2bf(W[k * 128 + j]);
}

__global__ void build_bsum(const float* __restrict__ b_ix, const float* __restrict__ b_ih,
                           const float* __restrict__ b_ux, const float* __restrict__ b_uh,
                           const float* __restrict__ b_ox, const float* __restrict__ b_oh,
                           const float* __restrict__ b_fx, const float* __restrict__ b_fh,
                           float* __restrict__ bsum)
{
  int n = blockIdx.x * 256 + threadIdx.x;   // 512
  int g = n >> 7, j = n & 127;
  float v = (g == 0) ? b_ix[j] + b_ih[j] : (g == 1) ? b_ux[j] + b_uh[j]
          : (g == 2) ? b_ox[j] + b_oh[j] : b_fx[j] + b_fh[j];
  bsum[n] = v;
}

__global__ void build_bt128(const float* __restrict__ W, u16* __restrict__ BT) {
  int idx = blockIdx.x * 256 + threadIdx.x;   // 128*128
  int n = idx >> 7, k = idx & 127;
  BT[idx] = f2bf(W[k * 128 + n]);
}

// ---------- output projection (4096 x 4, tiny) ----------
__global__ void out_proj(const u16* __restrict__ h_root, const float* __restrict__ W_out,
                         const float* __restrict__ b_out, float* __restrict__ out)
{
  int idx = blockIdx.x * 256 + threadIdx.x;   // 4096*4
  int n = idx >> 2, cls = idx & 3;
  float s = b_out[cls];
  for (int k = 0; k < 128; k++)
    s += bf2f(h_root[(long)n * 128 + k]) * W_out[k * 4 + cls];
  out[idx] = s;
}

extern "C" void kernel_launch(void* const* d_in, const int* in_sizes, int n_in,
                              void* d_out, int out_size, void* d_ws, size_t ws_size,
                              hipStream_t stream)
{
  const int*   sen  = (const int*)d_in[0];
  const float* emb  = (const float*)d_in[1];
  const float* W_ix = (const float*)d_in[2];  const float* b_ix = (const float*)d_in[3];
  const float* W_ih = (const float*)d_in[4];  const float* b_ih = (const float*)d_in[5];
  const float* W_fx = (const float*)d_in[6];  const float* b_fx = (const float*)d_in[7];
  const float* W_fh = (const float*)d_in[8];  const float* b_fh = (const float*)d_in[9];
  const float* W_ox = (const float*)d_in[10]; const float* b_ox = (const float*)d_in[11];
  const float* W_oh = (const float*)d_in[12]; const float* b_oh = (const float*)d_in[13];
  const float* W_ux = (const float*)d_in[14]; const float* b_ux = (const float*)d_in[15];
  const float* W_uh = (const float*)d_in[16]; const float* b_uh = (const float*)d_in[17];
  const float* W_out= (const float*)d_in[18]; const float* b_out= (const float*)d_in[19];
  float* out = (float*)d_out;

  // ---- workspace: arena A (L4/L2/L0 h+c), arena B (L3/L1 h+c), Ep, weights ----
  const size_t AH = (size_t)262144 * 128;   // u16 elems
  const size_t BH = (size_t)131072 * 128;
  const size_t EPB = (size_t)50000 * 512 * 2;
  const size_t need = 2 * AH * 2 + 2 * BH * 2 + EPB
                    + (size_t)512 * 128 * 2 + 4 * (size_t)128 * 128 * 2 + 512 * 4 + 8192;
  fprintf(stderr, "[tree_lstm] ws_size=%zu need=%zu\n", ws_size, need);
  if (ws_size < need) {
    fprintf(stderr, "[tree_lstm] INSUFFICIENT WORKSPACE — skipping launch\n");
    return;
  }
  char* ws = (char*)d_ws;
  size_t off = 0;
  auto take = [&](size_t bytes) { char* p = ws + off; off += (bytes + 255) & ~(size_t)255; return p; };
  u16* hA = (u16*)take(AH * 2);
  u16* cA = (u16*)take(AH * 2);
  u16* hB = (u16*)take(BH * 2);
  u16* cB = (u16*)take(BH * 2);
  u16* Ep = (u16*)take(EPB);
  u16* WallT = (u16*)take((size_t)512 * 128 * 2);
  u16* BihT = (u16*)take((size_t)128 * 128 * 2);
  u16* BuhT = (u16*)take((size_t)128 * 128 * 2);
  u16* BohT = (u16*)take((size_t)128 * 128 * 2);
  u16* BfhT = (u16*)take((size_t)128 * 128 * 2);
  float* bsum = (float*)take(512 * 4);

  // ---- prep ----
  build_wallT<<<256, 256, 0, stream>>>(W_ix, W_ux, W_ox, W_fx, WallT);
  build_bsum<<<2, 256, 0, stream>>>(b_ix, b_ih, b_ux, b_uh, b_ox, b_oh, b_fx, b_fh, bsum);
  build_bt128<<<64, 256, 0, stream>>>(W_ih, BihT);
  build_bt128<<<64, 256, 0, stream>>>(W_uh, BuhT);
  build_bt128<<<64, 256, 0, stream>>>(W_oh, BohT);
  build_bt128<<<64, 256, 0, stream>>>(W_fh, BfhT);
  proj_e<<<dim3(391, 4), 256, 0, stream>>>(emb, WallT, bsum, Ep);

  const long LOFF[6] = {0, 4096, 20480, 86016, 217088, 479232};

  // L4 (parents 262144, leaf children from Ep) -> A
  k_level<0, true><<<4096, 256, 0, stream>>>(sen, Ep, nullptr, nullptr,
      BfhT, BihT, BuhT, BohT, cA, hA, LOFF[4], LOFF[5]);
  // L3 (131072, ratio 2) A -> B
  k_level<1, false><<<2048, 256, 0, stream>>>(sen, Ep, hA, cA,
      BfhT, BihT, BuhT, BohT, cB, hB, LOFF[3], 0);
  // L2 (65536, ratio 2) B -> A
  k_level<1, false><<<1024, 256, 0, stream>>>(sen, Ep, hB, cB,
      BfhT, BihT, BuhT, BohT, cA, hA, LOFF[2], 0);
  // L1 (16384, ratio 4) A -> B
  k_level<2, false><<<512, 256, 0, stream>>>(sen, Ep, hA, cA,
      BfhT, BihT, BuhT, BohT, cB, hB, LOFF[1], 0);
  // L0 (4096, ratio 4) B -> A
  k_level<2, false><<<128, 256, 0, stream>>>(sen, Ep, hB, cB,
      BfhT, BihT, BuhT, BohT, cA, hA, LOFF[0], 0);

  out_proj<<<64, 256, 0, stream>>>(hA, W_out, b_out, out);
}

// Round 12
// 617.709 us; speedup vs baseline: 1.7786x; 1.7786x over previous
//
#include <hip/hip_runtime.h>
#include <hip/hip_bf16.h>
#include <cstdio>

typedef unsigned short u16;
typedef __bf16 bf16x8 __attribute__((ext_vector_type(8)));
typedef float  floatx4 __attribute__((ext_vector_type(4)));

// ---------- scalar helpers ----------
__device__ __forceinline__ float bf2f(u16 u) {
  union { unsigned int i; float f; } v; v.i = ((unsigned int)u) << 16; return v.f;
}
__device__ __forceinline__ u16 f2bf(float f) {
  union { float f; unsigned int i; } v; v.f = f;
  unsigned int x = v.i;
  return (u16)((x + 0x7fffu + ((x >> 16) & 1u)) >> 16);   // RNE
}
__device__ __forceinline__ unsigned int f2bf_pk(float a, float b) {   // [lo=a, hi=b]
  __hip_bfloat162 h = __float22bfloat162_rn(make_float2(a, b));
  union { __hip_bfloat162 h; unsigned int u; } v; v.h = h; return v.u;
}
// fast gates: v_rcp (~1 ulp) + native exp — no IEEE div
__device__ __forceinline__ float sigmoidf_(float x) {
  return __builtin_amdgcn_rcpf(1.f + __expf(-x));
}
__device__ __forceinline__ float tanhf_(float x) {
  return fmaf(-2.f, __builtin_amdgcn_rcpf(1.f + __expf(2.f * x)), 1.f);
}

// LDS swizzle, 128-elem rows, 16B chunks: chunk' = chunk ^ (row&15)
__device__ __forceinline__ int swz128(int row, int c16) {
  return row * 128 + ((c16 ^ (row & 15)) << 3);
}
// element-level access into swizzled rows
__device__ __forceinline__ int swze(int row, int col) {
  return row * 128 + (((((col >> 3)) ^ (row & 15)) << 3) | (col & 7));
}

// ============ proj_e: E'[v][512] = emb[v] @ [Wix|Wux|Wox|Wfx] + bias (bf16) ============
__global__ __launch_bounds__(256) void proj_e(
    const float* __restrict__ emb, const u16* __restrict__ WT,
    const float* __restrict__ bsum, u16* __restrict__ Ep)
{
  __shared__ __align__(16) u16 ldsA[128 * 128];
  const int tid = threadIdx.x;
  const long m0 = (long)blockIdx.x * 128;
  const int n0 = blockIdx.y * 128;
  {
    const int r = tid >> 1, half = tid & 1;
    long row = m0 + r; if (row > 49999) row = 49999;
    const float* src = emb + row * 128 + half * 64;
#pragma unroll
    for (int i = 0; i < 8; i++) {
      float4 v0 = *reinterpret_cast<const float4*>(src + i * 8);
      float4 v1 = *reinterpret_cast<const float4*>(src + i * 8 + 4);
      unsigned int ov[4] = { f2bf_pk(v0.x, v0.y), f2bf_pk(v0.z, v0.w),
                             f2bf_pk(v1.x, v1.y), f2bf_pk(v1.z, v1.w) };
      *reinterpret_cast<uint4*>(&ldsA[swz128(r, half * 8 + i)]) =
          *reinterpret_cast<const uint4*>(ov);
    }
  }
  __syncthreads();
  const int lane = tid & 63, w = tid >> 6, l16 = lane & 15, quad = lane >> 4;
#pragma unroll
  for (int gl = 0; gl < 2; gl++) {
    const int col = n0 + w * 32 + gl * 16 + l16;
    bf16x8 b[4];
#pragma unroll
    for (int ks = 0; ks < 4; ks++)
      b[ks] = *reinterpret_cast<const bf16x8*>(WT + (size_t)col * 128 + ks * 32 + quad * 8);
    floatx4 acc[8];
#pragma unroll
    for (int i = 0; i < 8; i++) acc[i] = (floatx4){0.f, 0.f, 0.f, 0.f};
#pragma unroll
    for (int ks = 0; ks < 4; ks++)
#pragma unroll
      for (int i = 0; i < 8; i++) {
        bf16x8 a = *reinterpret_cast<const bf16x8*>(&ldsA[swz128(i * 16 + l16, ks * 4 + quad)]);
        acc[i] = __builtin_amdgcn_mfma_f32_16x16x32_bf16(a, b[ks], acc[i], 0, 0, 0);
      }
    const float bb = bsum[col];
#pragma unroll
    for (int i = 0; i < 8; i++)
#pragma unroll
      for (int r2 = 0; r2 < 4; r2++) {
        const long row = m0 + i * 16 + quad * 4 + r2;
        if (row < 50000) Ep[row * 512 + col] = f2bf(acc[i][r2] + bb);
      }
  }
}

// ============ k_level: per-i-tile fused f/i/u/o — no cross-tile register state ============
// For each 16-row child tile: 1 ds_read feeds 4 MFMAs (one per gate); epilogue computes
// c AND h immediately (all gate sums available) -> LDS staging. Register pressure is
// independent of NCI (rounds 9-11 spilled ~300MB holding per-pass accumulator arrays).
template<int LR, bool LEAF>
__global__ __launch_bounds__(256, 2) void k_level(
    const int* __restrict__ sen, const u16* __restrict__ Ep,
    const u16* __restrict__ h_prev, const u16* __restrict__ c_prev,
    const u16* __restrict__ BfT, const u16* __restrict__ BihT,
    const u16* __restrict__ BuhT, const u16* __restrict__ BohT,
    u16* __restrict__ c_out, u16* __restrict__ h_out,
    long o0, long co0)
{
  constexpr int PM  = (LR == 2) ? 32 : 64;
  constexpr int CM  = PM << LR;
  constexpr int NCI = CM / 16;
  constexpr int RT  = 1 << LR;
  constexpr int RTI = 4 >> LR;         // parents per 4-row quad block
  constexpr int TPR = 256 / CM;        // staging threads per child row
  __shared__ __align__(16) u16 ldsA[CM * 128];     // child h (swz) — read-only in main loop
  __shared__ __align__(16) u16 ldsC[PM * 128];     // LEAF: child c -> parent c; else parent c
  __shared__ __align__(16) u16 hstage[PM * 128];   // parent h staging
  __shared__ int sidP[PM];

  const int tid = threadIdx.x;
  const long p0 = (long)blockIdx.x * PM;
  const long cb = (long)blockIdx.x * CM;

  // ---- stage children ----
  {
    const int r = tid / TPR, q = tid % TPR;
    constexpr int CH = 16 / TPR;
    if (LEAF) {
      const u16* e = Ep + (size_t)sen[co0 + cb + r] * 512;
#pragma unroll
      for (int ii = 0; ii < CH; ii++) {
        const int c16 = q * CH + ii;
        uint4 vi = *reinterpret_cast<const uint4*>(e + c16 * 8);
        uint4 vu = *reinterpret_cast<const uint4*>(e + 128 + c16 * 8);
        uint4 vo = *reinterpret_cast<const uint4*>(e + 256 + c16 * 8);
        const u16* pi = reinterpret_cast<const u16*>(&vi);
        const u16* pu = reinterpret_cast<const u16*>(&vu);
        const u16* po = reinterpret_cast<const u16*>(&vo);
        unsigned int hc[4], cc[4];
#pragma unroll
        for (int k = 0; k < 4; k++) {
          float cv0 = sigmoidf_(bf2f(pi[2*k]))   * tanhf_(bf2f(pu[2*k]));
          float cv1 = sigmoidf_(bf2f(pi[2*k+1])) * tanhf_(bf2f(pu[2*k+1]));
          float h0 = sigmoidf_(bf2f(po[2*k]))   * tanhf_(cv0);
          float h1 = sigmoidf_(bf2f(po[2*k+1])) * tanhf_(cv1);
          cc[k] = f2bf_pk(cv0, cv1);
          hc[k] = f2bf_pk(h0, h1);
        }
        *reinterpret_cast<uint4*>(&ldsA[swz128(r, c16)]) = *reinterpret_cast<const uint4*>(hc);
        *reinterpret_cast<uint4*>(&ldsC[swz128(r, c16)]) = *reinterpret_cast<const uint4*>(cc);
      }
    } else {
      const u16* src = h_prev + (cb + r) * 128;
#pragma unroll
      for (int ii = 0; ii < CH; ii++) {
        const int c16 = q * CH + ii;
        *reinterpret_cast<uint4*>(&ldsA[swz128(r, c16)]) =
            *reinterpret_cast<const uint4*>(src + c16 * 8);
      }
    }
    if (tid < PM) sidP[tid] = sen[o0 + p0 + tid];
  }
  __syncthreads();

  const int lane = tid & 63, w = tid >> 6, l16 = lane & 15, quad = lane >> 4;

#pragma unroll
  for (int gl = 0; gl < 2; gl++) {
    const int col = w * 32 + gl * 16 + l16;
    // B fragments for all four gates (reused across all i-tiles)
    bf16x8 bF[4], bI[4], bU[4], bO[4];
#pragma unroll
    for (int ks = 0; ks < 4; ks++) {
      const size_t bo_ = (size_t)col * 128 + ks * 32 + quad * 8;
      bF[ks] = *reinterpret_cast<const bf16x8*>(BfT + bo_);
      bI[ks] = *reinterpret_cast<const bf16x8*>(BihT + bo_);
      bU[ks] = *reinterpret_cast<const bf16x8*>(BuhT + bo_);
      bO[ks] = *reinterpret_cast<const bf16x8*>(BohT + bo_);
    }
#pragma unroll
    for (int i = 0; i < NCI; i++) {
      floatx4 aF = {0.f,0.f,0.f,0.f}, aI = {0.f,0.f,0.f,0.f};
      floatx4 aU = {0.f,0.f,0.f,0.f}, aO = {0.f,0.f,0.f,0.f};
#pragma unroll
      for (int ks = 0; ks < 4; ks++) {
        bf16x8 a = *reinterpret_cast<const bf16x8*>(&ldsA[swz128(i * 16 + l16, ks * 4 + quad)]);
        aF = __builtin_amdgcn_mfma_f32_16x16x32_bf16(a, bF[ks], aF, 0, 0, 0);
        aI = __builtin_amdgcn_mfma_f32_16x16x32_bf16(a, bI[ks], aI, 0, 0, 0);
        aU = __builtin_amdgcn_mfma_f32_16x16x32_bf16(a, bU[ks], aU, 0, 0, 0);
        aO = __builtin_amdgcn_mfma_f32_16x16x32_bf16(a, bO[ks], aO, 0, 0, 0);
      }
      const int rbase = i * 16 + quad * 4;
#pragma unroll
      for (int t = 0; t < RTI; t++) {
        const int p = (rbase >> LR) + t;
        const size_t eb = (size_t)sidP[p] * 512;
        const float epf = bf2f(Ep[eb + 384 + col]);
        float fsum = 0.f, isum = 0.f, usum = 0.f, osum = 0.f;
#pragma unroll
        for (int r2 = t * RT; r2 < t * RT + RT; r2++) {
          const int row = rbase + r2;
          const float cch = LEAF ? bf2f(ldsC[swze(row, col)])
                                 : bf2f(c_prev[(cb + row) * 128 + col]);
          fsum += sigmoidf_(aF[r2] + epf) * cch;
          isum += aI[r2]; usum += aU[r2]; osum += aO[r2];
        }
        const float preI = isum + bf2f(Ep[eb + col]);
        const float preU = usum + bf2f(Ep[eb + 128 + col]);
        const float c = sigmoidf_(preI) * tanhf_(preU) + fsum;
        const float h = sigmoidf_(osum + bf2f(Ep[eb + 256 + col])) * tanhf_(c);
        ldsC[swze(p, col)] = f2bf(c);     // same-lane ownership (LEAF: after child-c read)
        hstage[swze(p, col)] = f2bf(h);
      }
    }
  }
  __syncthreads();

  // ---- dense stores: c from ldsC, h from hstage ----
  u16* cdst = c_out + p0 * 128;
  u16* hdst = h_out + p0 * 128;
  for (int t = tid; t < PM * 16; t += 256) {
    const int r = t >> 4, c16 = t & 15;
    *reinterpret_cast<uint4*>(cdst + t * 8) = *reinterpret_cast<const uint4*>(&ldsC[swz128(r, c16)]);
    *reinterpret_cast<uint4*>(hdst + t * 8) = *reinterpret_cast<const uint4*>(&hstage[swz128(r, c16)]);
  }
}

// ---------- weight/bias prep ----------
__global__ void build_wallT(const float* __restrict__ Wix, const float* __restrict__ Wux,
                            const float* __restrict__ Wox, const float* __restrict__ Wfx,
                            u16* __restrict__ WT)
{
  int idx = blockIdx.x * 256 + threadIdx.x;   // 512*128
  int n = idx >> 7, k = idx & 127;
  int g = n >> 7, j = n & 127;
  const float* W = (g == 0) ? Wix : (g == 1) ? Wux : (g == 2) ? Wox : Wfx;
  WT[idx] = f2bf(W[k * 128 + j]);
}

__global__ void build_bsum(const float* __restrict__ b_ix, const float* __restrict__ b_ih,
                           const float* __restrict__ b_ux, const float* __restrict__ b_uh,
                           const float* __restrict__ b_ox, const float* __restrict__ b_oh,
                           const float* __restrict__ b_fx, const float* __restrict__ b_fh,
                           float* __restrict__ bsum)
{
  int n = blockIdx.x * 256 + threadIdx.x;   // 512
  int g = n >> 7, j = n & 127;
  float v = (g == 0) ? b_ix[j] + b_ih[j] : (g == 1) ? b_ux[j] + b_uh[j]
          : (g == 2) ? b_ox[j] + b_oh[j] : b_fx[j] + b_fh[j];
  bsum[n] = v;
}

__global__ void build_bt128(const float* __restrict__ W, u16* __restrict__ BT) {
  int idx = blockIdx.x * 256 + threadIdx.x;   // 128*128
  int n = idx >> 7, k = idx & 127;
  BT[idx] = f2bf(W[k * 128 + n]);
}

// ---------- output projection (4096 x 4, tiny) ----------
__global__ void out_proj(const u16* __restrict__ h_root, const float* __restrict__ W_out,
                         const float* __restrict__ b_out, float* __restrict__ out)
{
  int idx = blockIdx.x * 256 + threadIdx.x;   // 4096*4
  int n = idx >> 2, cls = idx & 3;
  float s = b_out[cls];
  for (int k = 0; k < 128; k++)
    s += bf2f(h_root[(long)n * 128 + k]) * W_out[k * 4 + cls];
  out[idx] = s;
}

extern "C" void kernel_launch(void* const* d_in, const int* in_sizes, int n_in,
                              void* d_out, int out_size, void* d_ws, size_t ws_size,
                              hipStream_t stream)
{
  const int*   sen  = (const int*)d_in[0];
  const float* emb  = (const float*)d_in[1];
  const float* W_ix = (const float*)d_in[2];  const float* b_ix = (const float*)d_in[3];
  const float* W_ih = (const float*)d_in[4];  const float* b_ih = (const float*)d_in[5];
  const float* W_fx = (const float*)d_in[6];  const float* b_fx = (const float*)d_in[7];
  const float* W_fh = (const float*)d_in[8];  const float* b_fh = (const float*)d_in[9];
  const float* W_ox = (const float*)d_in[10]; const float* b_ox = (const float*)d_in[11];
  const float* W_oh = (const float*)d_in[12]; const float* b_oh = (const float*)d_in[13];
  const float* W_ux = (const float*)d_in[14]; const float* b_ux = (const float*)d_in[15];
  const float* W_uh = (const float*)d_in[16]; const float* b_uh = (const float*)d_in[17];
  const float* W_out= (const float*)d_in[18]; const float* b_out= (const float*)d_in[19];
  float* out = (float*)d_out;

  // ---- workspace: arena A (L4/L2/L0 h+c), arena B (L3/L1 h+c), Ep, weights ----
  const size_t AH = (size_t)262144 * 128;   // u16 elems
  const size_t BH = (size_t)131072 * 128;
  const size_t EPB = (size_t)50000 * 512 * 2;
  const size_t need = 2 * AH * 2 + 2 * BH * 2 + EPB
                    + (size_t)512 * 128 * 2 + 4 * (size_t)128 * 128 * 2 + 512 * 4 + 8192;
  fprintf(stderr, "[tree_lstm] ws_size=%zu need=%zu\n", ws_size, need);
  if (ws_size < need) {
    fprintf(stderr, "[tree_lstm] INSUFFICIENT WORKSPACE — skipping launch\n");
    return;
  }
  char* ws = (char*)d_ws;
  size_t off = 0;
  auto take = [&](size_t bytes) { char* p = ws + off; off += (bytes + 255) & ~(size_t)255; return p; };
  u16* hA = (u16*)take(AH * 2);
  u16* cA = (u16*)take(AH * 2);
  u16* hB = (u16*)take(BH * 2);
  u16* cB = (u16*)take(BH * 2);
  u16* Ep = (u16*)take(EPB);
  u16* WallT = (u16*)take((size_t)512 * 128 * 2);
  u16* BihT = (u16*)take((size_t)128 * 128 * 2);
  u16* BuhT = (u16*)take((size_t)128 * 128 * 2);
  u16* BohT = (u16*)take((size_t)128 * 128 * 2);
  u16* BfhT = (u16*)take((size_t)128 * 128 * 2);
  float* bsum = (float*)take(512 * 4);

  // ---- prep ----
  build_wallT<<<256, 256, 0, stream>>>(W_ix, W_ux, W_ox, W_fx, WallT);
  build_bsum<<<2, 256, 0, stream>>>(b_ix, b_ih, b_ux, b_uh, b_ox, b_oh, b_fx, b_fh, bsum);
  build_bt128<<<64, 256, 0, stream>>>(W_ih, BihT);
  build_bt128<<<64, 256, 0, stream>>>(W_uh, BuhT);
  build_bt128<<<64, 256, 0, stream>>>(W_oh, BohT);
  build_bt128<<<64, 256, 0, stream>>>(W_fh, BfhT);
  proj_e<<<dim3(391, 4), 256, 0, stream>>>(emb, WallT, bsum, Ep);

  const long LOFF[6] = {0, 4096, 20480, 86016, 217088, 479232};

  // L4 (parents 262144, leaf children from Ep) -> A
  k_level<0, true><<<4096, 256, 0, stream>>>(sen, Ep, nullptr, nullptr,
      BfhT, BihT, BuhT, BohT, cA, hA, LOFF[4], LOFF[5]);
  // L3 (131072, ratio 2) A -> B
  k_level<1, false><<<2048, 256, 0, stream>>>(sen, Ep, hA, cA,
      BfhT, BihT, BuhT, BohT, cB, hB, LOFF[3], 0);
  // L2 (65536, ratio 2) B -> A
  k_level<1, false><<<1024, 256, 0, stream>>>(sen, Ep, hB, cB,
      BfhT, BihT, BuhT, BohT, cA, hA, LOFF[2], 0);
  // L1 (16384, ratio 4) A -> B
  k_level<2, false><<<512, 256, 0, stream>>>(sen, Ep, hA, cA,
      BfhT, BihT, BuhT, BohT, cB, hB, LOFF[1], 0);
  // L0 (4096, ratio 4) B -> A
  k_level<2, false><<<128, 256, 0, stream>>>(sen, Ep, hB, cB,
      BfhT, BihT, BuhT, BohT, cA, hA, LOFF[0], 0);

  out_proj<<<64, 256, 0, stream>>>(hA, W_out, b_out, out);
}

// Round 13
// 617.121 us; speedup vs baseline: 1.7803x; 1.0010x over previous
//
#include <hip/hip_runtime.h>
#include <hip/hip_bf16.h>
#include <cstdio>

typedef unsigned short u16;
typedef __bf16 bf16x8 __attribute__((ext_vector_type(8)));
typedef float  floatx4 __attribute__((ext_vector_type(4)));

// ---------- scalar helpers ----------
__device__ __forceinline__ float bf2f(u16 u) {
  union { unsigned int i; float f; } v; v.i = ((unsigned int)u) << 16; return v.f;
}
__device__ __forceinline__ u16 f2bf(float f) {
  union { float f; unsigned int i; } v; v.f = f;
  unsigned int x = v.i;
  return (u16)((x + 0x7fffu + ((x >> 16) & 1u)) >> 16);   // RNE
}
__device__ __forceinline__ unsigned int f2bf_pk(float a, float b) {   // [lo=a, hi=b]
  __hip_bfloat162 h = __float22bfloat162_rn(make_float2(a, b));
  union { __hip_bfloat162 h; unsigned int u; } v; v.h = h; return v.u;
}
// fast gates: v_rcp (~1 ulp) + native exp — no IEEE div
__device__ __forceinline__ float sigmoidf_(float x) {
  return __builtin_amdgcn_rcpf(1.f + __expf(-x));
}
__device__ __forceinline__ float tanhf_(float x) {
  return fmaf(-2.f, __builtin_amdgcn_rcpf(1.f + __expf(2.f * x)), 1.f);
}

// LDS swizzle, 128-elem rows, 16B chunks: chunk' = chunk ^ (row&15)
__device__ __forceinline__ int swz128(int row, int c16) {
  return row * 128 + ((c16 ^ (row & 15)) << 3);
}
// element-level access into swizzled rows
__device__ __forceinline__ int swze(int row, int col) {
  return row * 128 + (((((col >> 3)) ^ (row & 15)) << 3) | (col & 7));
}

// ============ proj_e: Ep[v][col][4] = {i,u,o,f} pre-acts + biases (gate-interleaved) ============
// One block: 128 vocab rows x 128 cols x all 4 gates -> ushort4 coalesced stores.
__global__ __launch_bounds__(256, 2) void proj_e(
    const float* __restrict__ emb, const u16* __restrict__ WT,
    const float* __restrict__ bsum, u16* __restrict__ Ep)
{
  __shared__ __align__(16) u16 ldsA[128 * 128];
  const int tid = threadIdx.x;
  const long m0 = (long)blockIdx.x * 128;
  {
    const int r = tid >> 1, half = tid & 1;
    long row = m0 + r; if (row > 49999) row = 49999;
    const float* src = emb + row * 128 + half * 64;
#pragma unroll
    for (int i = 0; i < 8; i++) {
      float4 v0 = *reinterpret_cast<const float4*>(src + i * 8);
      float4 v1 = *reinterpret_cast<const float4*>(src + i * 8 + 4);
      unsigned int ov[4] = { f2bf_pk(v0.x, v0.y), f2bf_pk(v0.z, v0.w),
                             f2bf_pk(v1.x, v1.y), f2bf_pk(v1.z, v1.w) };
      *reinterpret_cast<uint4*>(&ldsA[swz128(r, half * 8 + i)]) =
          *reinterpret_cast<const uint4*>(ov);
    }
  }
  __syncthreads();
  const int lane = tid & 63, w = tid >> 6, l16 = lane & 15, quad = lane >> 4;
#pragma unroll
  for (int half = 0; half < 2; half++) {
    const int col = w * 32 + half * 16 + l16;
    bf16x8 bI[4], bU[4], bO[4], bF[4];
#pragma unroll
    for (int ks = 0; ks < 4; ks++) {
      const size_t o_ = ks * 32 + quad * 8;
      bI[ks] = *reinterpret_cast<const bf16x8*>(WT + (size_t)(0   + col) * 128 + o_);
      bU[ks] = *reinterpret_cast<const bf16x8*>(WT + (size_t)(128 + col) * 128 + o_);
      bO[ks] = *reinterpret_cast<const bf16x8*>(WT + (size_t)(256 + col) * 128 + o_);
      bF[ks] = *reinterpret_cast<const bf16x8*>(WT + (size_t)(384 + col) * 128 + o_);
    }
    const float bi = bsum[col], bu = bsum[128 + col], bo = bsum[256 + col], bf = bsum[384 + col];
#pragma unroll
    for (int i = 0; i < 8; i++) {
      floatx4 aI = {0.f,0.f,0.f,0.f}, aU = {0.f,0.f,0.f,0.f};
      floatx4 aO = {0.f,0.f,0.f,0.f}, aF = {0.f,0.f,0.f,0.f};
#pragma unroll
      for (int ks = 0; ks < 4; ks++) {
        bf16x8 a = *reinterpret_cast<const bf16x8*>(&ldsA[swz128(i * 16 + l16, ks * 4 + quad)]);
        aI = __builtin_amdgcn_mfma_f32_16x16x32_bf16(a, bI[ks], aI, 0, 0, 0);
        aU = __builtin_amdgcn_mfma_f32_16x16x32_bf16(a, bU[ks], aU, 0, 0, 0);
        aO = __builtin_amdgcn_mfma_f32_16x16x32_bf16(a, bO[ks], aO, 0, 0, 0);
        aF = __builtin_amdgcn_mfma_f32_16x16x32_bf16(a, bF[ks], aF, 0, 0, 0);
      }
#pragma unroll
      for (int r2 = 0; r2 < 4; r2++) {
        const long row = m0 + i * 16 + quad * 4 + r2;
        if (row < 50000) {
          u16 ov[4] = { f2bf(aI[r2] + bi), f2bf(aU[r2] + bu),
                        f2bf(aO[r2] + bo), f2bf(aF[r2] + bf) };
          *reinterpret_cast<ushort4*>(Ep + row * 512 + col * 4) =
              *reinterpret_cast<const ushort4*>(ov);
        }
      }
    }
  }
}

// ============ k_level: per-i-tile fused f/i/u/o; gate-interleaved Ep; direct global c/h ============
template<int LR, bool LEAF>
__global__ __launch_bounds__(256, 2) void k_level(
    const int* __restrict__ sen, const u16* __restrict__ Ep,
    const u16* __restrict__ h_prev, const u16* __restrict__ c_prev,
    const u16* __restrict__ BfT, const u16* __restrict__ BihT,
    const u16* __restrict__ BuhT, const u16* __restrict__ BohT,
    u16* __restrict__ c_out, u16* __restrict__ h_out,
    long o0, long co0)
{
  constexpr int PM  = (LR == 2) ? 32 : 64;
  constexpr int CM  = PM << LR;
  constexpr int NCI = CM / 16;
  constexpr int RT  = 1 << LR;
  constexpr int RTI = 4 >> LR;         // parents per 4-row quad block
  constexpr int TPR = 256 / CM;        // staging threads per child row
  __shared__ __align__(16) u16 ldsA[CM * 128];            // child h (swz)
  __shared__ __align__(16) u16 ldsC[LEAF ? CM * 128 : 8]; // LEAF: child c (swz)
  __shared__ int sidP[PM];

  const int tid = threadIdx.x;
  const long p0 = (long)blockIdx.x * PM;
  const long cb = (long)blockIdx.x * CM;

  // ---- stage children ----
  {
    const int r = tid / TPR, q = tid % TPR;
    constexpr int CH = 16 / TPR;
    if (LEAF) {
      const u16* e = Ep + (size_t)sen[co0 + cb + r] * 512;   // [col][4] interleaved
#pragma unroll
      for (int ii = 0; ii < CH; ii++) {
        const int c16 = q * CH + ii;                          // 8-col chunk
        uint4 v[4];
#pragma unroll
        for (int k = 0; k < 4; k++)
          v[k] = *reinterpret_cast<const uint4*>(e + c16 * 32 + k * 8);   // 2 cols each
        unsigned int hc[4], cc[4];
#pragma unroll
        for (int k = 0; k < 4; k++) {   // col pair 2k, 2k+1
          const u16* p = reinterpret_cast<const u16*>(&v[k]);
          float cv0 = sigmoidf_(bf2f(p[0])) * tanhf_(bf2f(p[1]));
          float cv1 = sigmoidf_(bf2f(p[4])) * tanhf_(bf2f(p[5]));
          float h0 = sigmoidf_(bf2f(p[2])) * tanhf_(cv0);
          float h1 = sigmoidf_(bf2f(p[6])) * tanhf_(cv1);
          cc[k] = f2bf_pk(cv0, cv1);
          hc[k] = f2bf_pk(h0, h1);
        }
        *reinterpret_cast<uint4*>(&ldsA[swz128(r, c16)]) = *reinterpret_cast<const uint4*>(hc);
        *reinterpret_cast<uint4*>(&ldsC[swz128(r, c16)]) = *reinterpret_cast<const uint4*>(cc);
      }
    } else {
      const u16* src = h_prev + (cb + r) * 128;
#pragma unroll
      for (int ii = 0; ii < CH; ii++) {
        const int c16 = q * CH + ii;
        *reinterpret_cast<uint4*>(&ldsA[swz128(r, c16)]) =
            *reinterpret_cast<const uint4*>(src + c16 * 8);
      }
    }
    if (tid < PM) sidP[tid] = sen[o0 + p0 + tid];
  }
  __syncthreads();

  const int lane = tid & 63, w = tid >> 6, l16 = lane & 15, quad = lane >> 4;

#pragma unroll
  for (int gl = 0; gl < 2; gl++) {
    const int col = w * 32 + gl * 16 + l16;
    bf16x8 bF[4], bI[4], bU[4], bO[4];
#pragma unroll
    for (int ks = 0; ks < 4; ks++) {
      const size_t bo_ = (size_t)col * 128 + ks * 32 + quad * 8;
      bF[ks] = *reinterpret_cast<const bf16x8*>(BfT + bo_);
      bI[ks] = *reinterpret_cast<const bf16x8*>(BihT + bo_);
      bU[ks] = *reinterpret_cast<const bf16x8*>(BuhT + bo_);
      bO[ks] = *reinterpret_cast<const bf16x8*>(BohT + bo_);
    }
#pragma unroll
    for (int i = 0; i < NCI; i++) {
      floatx4 aF = {0.f,0.f,0.f,0.f}, aI = {0.f,0.f,0.f,0.f};
      floatx4 aU = {0.f,0.f,0.f,0.f}, aO = {0.f,0.f,0.f,0.f};
#pragma unroll
      for (int ks = 0; ks < 4; ks++) {
        bf16x8 a = *reinterpret_cast<const bf16x8*>(&ldsA[swz128(i * 16 + l16, ks * 4 + quad)]);
        aF = __builtin_amdgcn_mfma_f32_16x16x32_bf16(a, bF[ks], aF, 0, 0, 0);
        aI = __builtin_amdgcn_mfma_f32_16x16x32_bf16(a, bI[ks], aI, 0, 0, 0);
        aU = __builtin_amdgcn_mfma_f32_16x16x32_bf16(a, bU[ks], aU, 0, 0, 0);
        aO = __builtin_amdgcn_mfma_f32_16x16x32_bf16(a, bO[ks], aO, 0, 0, 0);
      }
      const int rbase = i * 16 + quad * 4;
#pragma unroll
      for (int t = 0; t < RTI; t++) {
        const int p = (rbase >> LR) + t;
        // one 8-B load fetches all four gate pre-acts {i,u,o,f} for (parent, col)
        ushort4 g4 = *reinterpret_cast<const ushort4*>(Ep + (size_t)sidP[p] * 512 + col * 4);
        const float epf = bf2f(g4.w);
        float fsum = 0.f, isum = 0.f, usum = 0.f, osum = 0.f;
#pragma unroll
        for (int r2 = t * RT; r2 < t * RT + RT; r2++) {
          const int row = rbase + r2;
          const float cch = LEAF ? bf2f(ldsC[swze(row, col)])
                                 : bf2f(c_prev[(cb + row) * 128 + col]);
          fsum += sigmoidf_(aF[r2] + epf) * cch;
          isum += aI[r2]; usum += aU[r2]; osum += aO[r2];
        }
        const float c = sigmoidf_(isum + bf2f(g4.x)) * tanhf_(usum + bf2f(g4.y)) + fsum;
        const float h = sigmoidf_(osum + bf2f(g4.z)) * tanhf_(c);
        c_out[(p0 + p) * 128 + col] = f2bf(c);
        h_out[(p0 + p) * 128 + col] = f2bf(h);
      }
    }
  }
}

// ---------- weight/bias prep ----------
__global__ void build_wallT(const float* __restrict__ Wix, const float* __restrict__ Wux,
                            const float* __restrict__ Wox, const float* __restrict__ Wfx,
                            u16* __restrict__ WT)
{
  int idx = blockIdx.x * 256 + threadIdx.x;   // 512*128
  int n = idx >> 7, k = idx & 127;
  int g = n >> 7, j = n & 127;
  const float* W = (g == 0) ? Wix : (g == 1) ? Wux : (g == 2) ? Wox : Wfx;
  WT[idx] = f2bf(W[k * 128 + j]);
}

__global__ void build_bsum(const float* __restrict__ b_ix, const float* __restrict__ b_ih,
                           const float* __restrict__ b_ux, const float* __restrict__ b_uh,
                           const float* __restrict__ b_ox, const float* __restrict__ b_oh,
                           const float* __restrict__ b_fx, const float* __restrict__ b_fh,
                           float* __restrict__ bsum)
{
  int n = blockIdx.x * 256 + threadIdx.x;   // 512
  int g = n >> 7, j = n & 127;
  float v = (g == 0) ? b_ix[j] + b_ih[j] : (g == 1) ? b_ux[j] + b_uh[j]
          : (g == 2) ? b_ox[j] + b_oh[j] : b_fx[j] + b_fh[j];
  bsum[n] = v;
}

__global__ void build_bt128(const float* __restrict__ W, u16* __restrict__ BT) {
  int idx = blockIdx.x * 256 + threadIdx.x;   // 128*128
  int n = idx >> 7, k = idx & 127;
  BT[idx] = f2bf(W[k * 128 + n]);
}

// ---------- output projection (4096 x 4, tiny) ----------
__global__ void out_proj(const u16* __restrict__ h_root, const float* __restrict__ W_out,
                         const float* __restrict__ b_out, float* __restrict__ out)
{
  int idx = blockIdx.x * 256 + threadIdx.x;   // 4096*4
  int n = idx >> 2, cls = idx & 3;
  float s = b_out[cls];
  for (int k = 0; k < 128; k++)
    s += bf2f(h_root[(long)n * 128 + k]) * W_out[k * 4 + cls];
  out[idx] = s;
}

extern "C" void kernel_launch(void* const* d_in, const int* in_sizes, int n_in,
                              void* d_out, int out_size, void* d_ws, size_t ws_size,
                              hipStream_t stream)
{
  const int*   sen  = (const int*)d_in[0];
  const float* emb  = (const float*)d_in[1];
  const float* W_ix = (const float*)d_in[2];  const float* b_ix = (const float*)d_in[3];
  const float* W_ih = (const float*)d_in[4];  const float* b_ih = (const float*)d_in[5];
  const float* W_fx = (const float*)d_in[6];  const float* b_fx = (const float*)d_in[7];
  const float* W_fh = (const float*)d_in[8];  const float* b_fh = (const float*)d_in[9];
  const float* W_ox = (const float*)d_in[10]; const float* b_ox = (const float*)d_in[11];
  const float* W_oh = (const float*)d_in[12]; const float* b_oh = (const float*)d_in[13];
  const float* W_ux = (const float*)d_in[14]; const float* b_ux = (const float*)d_in[15];
  const float* W_uh = (const float*)d_in[16]; const float* b_uh = (const float*)d_in[17];
  const float* W_out= (const float*)d_in[18]; const float* b_out= (const float*)d_in[19];
  float* out = (float*)d_out;

  // ---- workspace: arena A (L4/L2/L0 h+c), arena B (L3/L1 h+c), Ep, weights ----
  const size_t AH = (size_t)262144 * 128;   // u16 elems
  const size_t BH = (size_t)131072 * 128;
  const size_t EPB = (size_t)50000 * 512 * 2;
  const size_t need = 2 * AH * 2 + 2 * BH * 2 + EPB
                    + (size_t)512 * 128 * 2 + 4 * (size_t)128 * 128 * 2 + 512 * 4 + 8192;
  fprintf(stderr, "[tree_lstm] ws_size=%zu need=%zu\n", ws_size, need);
  if (ws_size < need) {
    fprintf(stderr, "[tree_lstm] INSUFFICIENT WORKSPACE — skipping launch\n");
    return;
  }
  char* ws = (char*)d_ws;
  size_t off = 0;
  auto take = [&](size_t bytes) { char* p = ws + off; off += (bytes + 255) & ~(size_t)255; return p; };
  u16* hA = (u16*)take(AH * 2);
  u16* cA = (u16*)take(AH * 2);
  u16* hB = (u16*)take(BH * 2);
  u16* cB = (u16*)take(BH * 2);
  u16* Ep = (u16*)take(EPB);
  u16* WallT = (u16*)take((size_t)512 * 128 * 2);
  u16* BihT = (u16*)take((size_t)128 * 128 * 2);
  u16* BuhT = (u16*)take((size_t)128 * 128 * 2);
  u16* BohT = (u16*)take((size_t)128 * 128 * 2);
  u16* BfhT = (u16*)take((size_t)128 * 128 * 2);
  float* bsum = (float*)take(512 * 4);

  // ---- prep ----
  build_wallT<<<256, 256, 0, stream>>>(W_ix, W_ux, W_ox, W_fx, WallT);
  build_bsum<<<2, 256, 0, stream>>>(b_ix, b_ih, b_ux, b_uh, b_ox, b_oh, b_fx, b_fh, bsum);
  build_bt128<<<64, 256, 0, stream>>>(W_ih, BihT);
  build_bt128<<<64, 256, 0, stream>>>(W_uh, BuhT);
  build_bt128<<<64, 256, 0, stream>>>(W_oh, BohT);
  build_bt128<<<64, 256, 0, stream>>>(W_fh, BfhT);
  proj_e<<<391, 256, 0, stream>>>(emb, WallT, bsum, Ep);

  const long LOFF[6] = {0, 4096, 20480, 86016, 217088, 479232};

  // L4 (parents 262144, leaf children from Ep) -> A
  k_level<0, true><<<4096, 256, 0, stream>>>(sen, Ep, nullptr, nullptr,
      BfhT, BihT, BuhT, BohT, cA, hA, LOFF[4], LOFF[5]);
  // L3 (131072, ratio 2) A -> B
  k_level<1, false><<<2048, 256, 0, stream>>>(sen, Ep, hA, cA,
      BfhT, BihT, BuhT, BohT, cB, hB, LOFF[3], 0);
  // L2 (65536, ratio 2) B -> A
  k_level<1, false><<<1024, 256, 0, stream>>>(sen, Ep, hB, cB,
      BfhT, BihT, BuhT, BohT, cA, hA, LOFF[2], 0);
  // L1 (16384, ratio 4) A -> B
  k_level<2, false><<<512, 256, 0, stream>>>(sen, Ep, hA, cA,
      BfhT, BihT, BuhT, BohT, cB, hB, LOFF[1], 0);
  // L0 (4096, ratio 4) B -> A
  k_level<2, false><<<128, 256, 0, stream>>>(sen, Ep, hB, cB,
      BfhT, BihT, BuhT, BohT, cA, hA, LOFF[0], 0);

  out_proj<<<64, 256, 0, stream>>>(hA, W_out, b_out, out);
}